// Round 9
// baseline (487.265 us; speedup 1.0000x reference)
//
#include <hip/hip_runtime.h>

#define N_NODES 100000
#define N_EDGES 1600000
#define C_DIM   128
#define R_TYPES 7
#define T_TYPES 4
#define SEGS    (N_NODES * R_TYPES)          // 700000 (dst,rel) segments
#define NB_E    (N_EDGES / 256)              // 6250 (E % 256 == 0)
#define NB_N    ((N_NODES + 255) / 256)      // 391 node blocks (also dst-scan blocks)
#define XP_ROWS 100096                       // N padded: /64 = 1564 exact, /128 = 782
#define DST_PART 12500                       // N / 8 (exact)
#define NB_ROOT ((N_NODES + 63) / 64)        // 1563 root blocks (64 nodes each)

// ---- workspace layout (bytes) ----
#define OFF_CNTI   0ull                       // int  cnti[SEGS]            2.80 MB
#define OFF_INV    2800000ull                 // f32  inv[SEGS]             2.80 MB
#define OFF_DOFF   5600000ull                 // int  dst_off[N+1]          0.40 MB
#define OFF_CURS   6000004ull                 // int  cursor[N]             0.40 MB
#define OFF_MISC   6400004ull                 // int  misc[32]   (unused now)
#define OFF_PERM   6400132ull                 // REUSED: bf16 wrf[8*16384] = 256 KB
#define PERM_CAP   100288
#define OFF_BLKN   6801284ull                 // (unused now)
#define OFF_BSUM   6813796ull                 // int  bsum[NB_N]
#define OFF_ESRC   6815360ull                 // int  esrc[E] packed r<<20|(r*XP_ROWS+src)
#define OFF_XP     13215360ull                // (unused now -- GEMM reads x directly)
#define OFF_WF     38839936ull                // bf16 wf[7*128*128] frag        0.23 MB
#define OFF_XWB    39069312ull                // bf16 xwb: full = 7 planes, fallback = 1
#define XWB_PLANE  ((size_t)XP_ROWS * 128)    // elements per relation plane
#define FULL_NEED  218441344ull               // OFF_XWB + 7*25,624,576
#define FB_NEED    64693888ull                // OFF_XWB + 1*25,624,576
#define OFF_WRF    OFF_PERM                   // root hi/lo W frags (256 KB)

typedef __attribute__((ext_vector_type(8))) short short8;
typedef __attribute__((ext_vector_type(4))) float f32x4;
typedef __attribute__((ext_vector_type(4))) unsigned short ushort4v;

__device__ inline unsigned short f2bf(float f) {
    unsigned int u = __float_as_uint(f);
    u += 0x7fffu + ((u >> 16) & 1u);          // RNE
    return (unsigned short)(u >> 16);
}
__device__ inline float bf2f(unsigned int h) { return __uint_as_float(h << 16); }

// ---------------- per-(dst,rel) counts ----------------
__global__ void edge_hist(const int* __restrict__ ei, const int* __restrict__ et,
                          int* __restrict__ cnti) {
    int e = blockIdx.x * 256 + threadIdx.x;
    atomicAdd(&cnti[ei[N_EDGES + e] * R_TYPES + et[e]], 1);   // 700k addrs: low contention
}

__global__ void inv_kernel(const int* __restrict__ cnti, float* __restrict__ inv) {
    int i = blockIdx.x * blockDim.x + threadIdx.x;
    if (i < SEGS) inv[i] = 1.0f / (float)max(cnti[i], 1);
}

// ---------------- dst-CSR: dst_off = exclusive scan of per-dst degree ----------------
__global__ void dst_scan1(const int* __restrict__ cnti, int* __restrict__ dst_off,
                          int* __restrict__ bsum) {
    __shared__ int sbuf[256];
    int tid = threadIdx.x;
    int i = blockIdx.x * 256 + tid;
    int v = 0;
    if (i < N_NODES) {
        #pragma unroll
        for (int r = 0; r < R_TYPES; ++r) v += cnti[i * R_TYPES + r];
    }
    sbuf[tid] = v;
    __syncthreads();
    #pragma unroll
    for (int off = 1; off < 256; off <<= 1) {
        int t = (tid >= off) ? sbuf[tid - off] : 0;
        __syncthreads();
        sbuf[tid] += t;
        __syncthreads();
    }
    int incl = sbuf[tid];
    if (i < N_NODES) dst_off[i] = incl - v;   // exclusive within chunk
    if (tid == 255) bsum[blockIdx.x] = incl;
}

__global__ void seg_scan2(int* __restrict__ bsum, int nb) {   // 1 block
    __shared__ int sbuf[256];
    int tid = threadIdx.x;
    int running = 0;
    for (int c0 = 0; c0 < nb; c0 += 256) {
        int b = c0 + tid;
        int v = (b < nb) ? bsum[b] : 0;
        sbuf[tid] = v;
        __syncthreads();
        #pragma unroll
        for (int off = 1; off < 256; off <<= 1) {
            int t = (tid >= off) ? sbuf[tid - off] : 0;
            __syncthreads();
            sbuf[tid] += t;
            __syncthreads();
        }
        int incl = sbuf[tid];
        int tot = sbuf[255];
        __syncthreads();
        if (b < nb) bsum[b] = running + incl - v;
        running += tot;
    }
}

__global__ void dst_scan3(int* __restrict__ dst_off, int* __restrict__ cursor,
                          const int* __restrict__ bsum) {
    int i = blockIdx.x * 256 + threadIdx.x;
    if (i < N_NODES) {
        int val = dst_off[i] + bsum[blockIdx.x];
        dst_off[i] = val;
        cursor[i] = val;
    }
    if (i == 0) dst_off[N_NODES] = N_EDGES;
}

// XCD-partitioned placement: block b = chunk (b>>3) x partition (b&7).
__global__ void place_edges(const int* __restrict__ ei, const int* __restrict__ et,
                            int* __restrict__ cursor, int* __restrict__ esrc) {
    int p = blockIdx.x & 7;
    int e = (blockIdx.x >> 3) * 256 + threadIdx.x;
    int d = ei[N_EDGES + e];
    if (d / DST_PART != p) return;
    int pos = atomicAdd(&cursor[d], 1);
    int r = et[e];
    esrc[pos] = (r << 20) | (r * XP_ROWS + ei[e]);   // r in [20:23), rowidx in [0:20)
}

// ---------------- bf16 fragment-layout conversions ----------------
__global__ void cvt_w_frag(const float* __restrict__ rel_w, unsigned short* __restrict__ wf) {
    int id = blockIdx.x * 256 + threadIdx.x;       // 7*128*16 = 14336 exact
    if (id >= R_TYPES * 128 * 16) return;
    int r = id >> 11, rest = id & 2047;
    int o = rest >> 4, ko = rest & 15;
    const float4* pw = (const float4*)(rel_w + (size_t)r * 16384 + o * 128 + ko * 8);
    float4 a = pw[0], b = pw[1];
    short8 v;
    v[0] = (short)f2bf(a.x); v[1] = (short)f2bf(a.y);
    v[2] = (short)f2bf(a.z); v[3] = (short)f2bf(a.w);
    v[4] = (short)f2bf(b.x); v[5] = (short)f2bf(b.y);
    v[6] = (short)f2bf(b.z); v[7] = (short)f2bf(b.w);
    size_t off = (size_t)r * 16384 + (o >> 4) * 2048 + (ko >> 2) * 512 + (ko & 3) * 128 + (o & 15) * 8;
    *(short8*)(wf + off) = v;
}

// root_w -> MFMA frag layout, hi plane [0..3] and lo plane [4..7] (hi/lo bf16 split)
__global__ void cvt_rootw_frag(const float* __restrict__ root_w, unsigned short* __restrict__ wrf) {
    int id = blockIdx.x * 256 + threadIdx.x;       // 4*128*16 = 8192 exact
    if (id >= T_TYPES * 128 * 16) return;
    int t = id >> 11, rest = id & 2047;
    int o = rest >> 4, ko = rest & 15;
    const float4* pw = (const float4*)(root_w + (size_t)t * 16384 + o * 128 + ko * 8);
    float4 a = pw[0], b = pw[1];
    float v[8] = {a.x, a.y, a.z, a.w, b.x, b.y, b.z, b.w};
    short8 hi, lo;
    #pragma unroll
    for (int j = 0; j < 8; ++j) {
        unsigned short h = f2bf(v[j]);
        hi[j] = (short)h;
        lo[j] = (short)f2bf(v[j] - bf2f(h));
    }
    size_t off = (size_t)t * 16384 + (o >> 4) * 2048 + (ko >> 2) * 512 + (ko & 3) * 128 + (o & 15) * 8;
    *(short8*)(wrf + off) = hi;
    *(short8*)(wrf + (size_t)T_TYPES * 16384 + off) = lo;
}

// ---------------- root linear, natural order, OPERAND-SWAPPED MFMA ----------
// Runs LAST (RMW onto gather's output). mfma(W_frag, x_frag): D row = channel,
// D col = node -> each thread owns ONE node and 4 consecutive channels per ct.
// out RMW becomes 8 float4 loads + 8 float4 stores per tile (was 32+32 scalar).
// RMW loads issued up front to hide under the 96-MFMA block.
__launch_bounds__(256)
__global__ void root_nat(const float* __restrict__ x, const unsigned short* __restrict__ wrf,
                         const float* __restrict__ root_b, const int* __restrict__ tnt,
                         float* __restrict__ out) {
    __shared__ int cnt[T_TYPES];
    __shared__ int goff[T_TYPES];
    __shared__ int rankb[64];
    __shared__ int lidx[112];          // 7 tiles x 16 rows max
    __shared__ int ttyp[8];
    __shared__ int ntile_s;
    int tid = threadIdx.x;
    int base = blockIdx.x * 64;
    if (tid < T_TYPES) cnt[tid] = 0;
    if (tid < 112) lidx[tid] = -1;
    __syncthreads();
    int myt = -1;
    if (tid < 64 && base + tid < N_NODES) {
        myt = tnt[base + tid];
        rankb[tid] = atomicAdd(&cnt[myt], 1);
    }
    __syncthreads();
    if (tid == 0) {
        int s = 0;
        for (int t = 0; t < T_TYPES; ++t) {
            goff[t] = s;
            int nt = (cnt[t] + 15) >> 4;
            for (int k = 0; k < nt; ++k) ttyp[(s >> 4) + k] = t;
            s += nt << 4;
        }
        ntile_s = s >> 4;
    }
    __syncthreads();
    if (myt >= 0) lidx[goff[myt] + rankb[tid]] = base + tid;
    __syncthreads();
    int ntiles = ntile_s;

    int wave = tid >> 6, lane = tid & 63;
    int l16 = lane & 15, kq = lane >> 4;
    int rq = kq * 4;                               // channel sub-offset within ct tile
    for (int tile = wave; tile < ntiles; tile += 4) {
        int t = ttyp[tile];
        int node = lidx[tile * 16 + l16];          // this thread's node (B col)

        // (1) out-RMW loads up front: 8 float4, latency hides under MFMA
        float4 ov[8];
        #pragma unroll
        for (int ct = 0; ct < 8; ++ct)
            ov[ct] = (node >= 0)
                   ? *(const float4*)(out + (size_t)node * C_DIM + ct * 16 + rq)
                   : make_float4(0.f, 0.f, 0.f, 0.f);

        // (2) x hi/lo B-fragments
        short8 xh[4], xl[4];
        #pragma unroll
        for (int kb = 0; kb < 4; ++kb) {
            float v[8];
            if (node >= 0) {
                const float4* px = (const float4*)(x + (size_t)node * C_DIM + kb * 32 + kq * 8);
                float4 p0 = px[0], p1 = px[1];
                v[0] = p0.x; v[1] = p0.y; v[2] = p0.z; v[3] = p0.w;
                v[4] = p1.x; v[5] = p1.y; v[6] = p1.z; v[7] = p1.w;
            } else {
                #pragma unroll
                for (int j = 0; j < 8; ++j) v[j] = 0.0f;
            }
            #pragma unroll
            for (int j = 0; j < 8; ++j) {
                unsigned short h = f2bf(v[j]);
                xh[kb][j] = (short)h;
                xl[kb][j] = (short)f2bf(v[j] - bf2f(h));
            }
        }

        // (3) 8 independent MFMA chains; A = W hi/lo frags
        const unsigned short* wh = wrf + (size_t)t * 16384;
        const unsigned short* wl = wh + (size_t)T_TYPES * 16384;
        f32x4 acc[8];
        #pragma unroll
        for (int ct = 0; ct < 8; ++ct) acc[ct] = (f32x4)0.0f;
        #pragma unroll
        for (int kb = 0; kb < 4; ++kb) {
            #pragma unroll
            for (int ct = 0; ct < 8; ++ct) {
                short8 ah = *(const short8*)(wh + ct * 2048 + kb * 512 + lane * 8);
                short8 alw = *(const short8*)(wl + ct * 2048 + kb * 512 + lane * 8);
                acc[ct] = __builtin_amdgcn_mfma_f32_16x16x32_bf16(ah, xh[kb], acc[ct], 0, 0, 0);
                acc[ct] = __builtin_amdgcn_mfma_f32_16x16x32_bf16(alw, xh[kb], acc[ct], 0, 0, 0);
                acc[ct] = __builtin_amdgcn_mfma_f32_16x16x32_bf16(ah, xl[kb], acc[ct], 0, 0, 0);
            }
        }

        // (4) bias (L2-hot) + add + float4 store
        if (node >= 0) {
            #pragma unroll
            for (int ct = 0; ct < 8; ++ct) {
                float4 bs = *(const float4*)(root_b + t * 128 + ct * 16 + rq);
                float4 w = make_float4(ov[ct].x + acc[ct][0] + bs.x,
                                       ov[ct].y + acc[ct][1] + bs.y,
                                       ov[ct].z + acc[ct][2] + bs.z,
                                       ov[ct].w + acc[ct][3] + bs.w);
                *(float4*)(out + (size_t)node * C_DIM + ct * 16 + rq) = w;
            }
        }
    }
}

// ---------------- fused MFMA GEMM, all 7 relations, OPERAND-SWAPPED ------------
// mfma(W_frag, x_frag): D row = channel, D col = node. Each thread owns one
// node; per (r,ct) it packs 4 consecutive bf16 channels -> one 8B store.
// Store instructions drop 8x vs the row-orientation (448 -> 56 per thread).
// 64-node blocks, grid 1564. Pad nodes store into pad rows (never read).
__launch_bounds__(256)
__global__ void xw_gemm_all(const float* __restrict__ x,
                            const unsigned short* __restrict__ wf,
                            unsigned short* __restrict__ xwb7) {
    int wave = threadIdx.x >> 6, lane = threadIdx.x & 63;
    int m0 = blockIdx.x * 64;
    int l16 = lane & 15, kq = lane >> 4;
    int rq = kq * 4;

    int node = m0 + wave * 16 + l16;               // this thread's node (B col)
    bool ok = node < N_NODES;
    short8 b[4];
    #pragma unroll
    for (int kb = 0; kb < 4; ++kb) {
        float v[8];
        if (ok) {
            const float4* px = (const float4*)(x + (size_t)node * C_DIM + kb * 32 + kq * 8);
            float4 p0 = px[0], p1 = px[1];
            v[0] = p0.x; v[1] = p0.y; v[2] = p0.z; v[3] = p0.w;
            v[4] = p1.x; v[5] = p1.y; v[6] = p1.z; v[7] = p1.w;
        } else {
            #pragma unroll
            for (int j = 0; j < 8; ++j) v[j] = 0.0f;
        }
        #pragma unroll
        for (int j = 0; j < 8; ++j) b[kb][j] = (short)f2bf(v[j]);
    }

    for (int r = 0; r < R_TYPES; ++r) {
        const unsigned short* wr = wf + (size_t)r * 16384;
        unsigned short* xwb = xwb7 + (size_t)r * XWB_PLANE;
        #pragma unroll
        for (int ct = 0; ct < 8; ++ct) {
            f32x4 acc = (f32x4)0.0f;
            #pragma unroll
            for (int kb = 0; kb < 4; ++kb) {
                short8 a = *(const short8*)(wr + (size_t)ct * 2048 + kb * 512 + lane * 8);
                acc = __builtin_amdgcn_mfma_f32_16x16x32_bf16(a, b[kb], acc, 0, 0, 0);
            }
            ushort4v pv;
            pv[0] = f2bf(acc[0]); pv[1] = f2bf(acc[1]);
            pv[2] = f2bf(acc[2]); pv[3] = f2bf(acc[3]);
            *(ushort4v*)(xwb + (size_t)node * C_DIM + ct * 16 + rq) = pv;  // 8B store
        }
    }
}

// fallback per-relation GEMM (single plane), A read directly from x (128-row blocks)
__launch_bounds__(256)
__global__ void xw_gemm_mfma(const float* __restrict__ x,
                             const unsigned short* __restrict__ wf,
                             unsigned short* __restrict__ xwb, int r) {
    int wave = threadIdx.x >> 6, lane = threadIdx.x & 63;
    int m0 = blockIdx.x * 128;
    int l16 = lane & 15, kq = lane >> 4;
    const unsigned short* wr = wf + (size_t)r * 16384;

    short8 a[4][2];
    #pragma unroll
    for (int rt = 0; rt < 2; ++rt) {
        int row = m0 + wave * 32 + rt * 16 + l16;
        bool ok = row < N_NODES;
        #pragma unroll
        for (int kb = 0; kb < 4; ++kb) {
            float v[8];
            if (ok) {
                const float4* px = (const float4*)(x + (size_t)row * C_DIM + kb * 32 + kq * 8);
                float4 p0 = px[0], p1 = px[1];
                v[0] = p0.x; v[1] = p0.y; v[2] = p0.z; v[3] = p0.w;
                v[4] = p1.x; v[5] = p1.y; v[6] = p1.z; v[7] = p1.w;
            } else {
                #pragma unroll
                for (int j = 0; j < 8; ++j) v[j] = 0.0f;
            }
            #pragma unroll
            for (int j = 0; j < 8; ++j) a[kb][rt][j] = (short)f2bf(v[j]);
        }
    }

    int col = l16, rq = kq * 4;
    #pragma unroll
    for (int ct = 0; ct < 8; ++ct) {
        f32x4 acc0 = (f32x4)0.0f, acc1 = (f32x4)0.0f;
        #pragma unroll
        for (int kb = 0; kb < 4; ++kb) {
            short8 b = *(const short8*)(wr + (size_t)ct * 2048 + kb * 512 + lane * 8);
            acc0 = __builtin_amdgcn_mfma_f32_16x16x32_bf16(a[kb][0], b, acc0, 0, 0, 0);
            acc1 = __builtin_amdgcn_mfma_f32_16x16x32_bf16(a[kb][1], b, acc1, 0, 0, 0);
        }
        #pragma unroll
        for (int i = 0; i < 4; ++i) {
            int n0 = m0 + wave * 32 + rq + i;
            if (n0 < N_NODES)
                xwb[(size_t)n0 * C_DIM + ct * 16 + col] = f2bf(acc0[i]);
            int n1 = n0 + 16;
            if (n1 < N_NODES)
                xwb[(size_t)n1 * C_DIM + ct * 16 + col] = f2bf(acc1[i]);
        }
    }
}

// ---------------- fused gather: out[d] = sum over d's edges of xwb7[r][src]*inv
// 16 edges per main iteration: 4 independent uint4 row loads in flight per wave
// (quarter-lane layout: 16 lanes x 16B per row). esrc prefetched one iteration
// ahead. Tail issues its group loads independently. Pure overwrite.
__global__ void gather_fused(const int* __restrict__ dst_off, const int* __restrict__ esrc,
                             const float* __restrict__ inv,
                             const unsigned short* __restrict__ xwb7,
                             float* __restrict__ out) {
    int wave = threadIdx.x >> 6, lane = threadIdx.x & 63;
    int d = blockIdx.x * 4 + wave;
    if (d >= N_NODES) return;
    int o0 = dst_off[d], o1 = dst_off[d + 1];
    int q = lane >> 4;               // quarter: which edge of a 4-group
    int l16 = lane & 15;
    const float* invd = inv + d * R_TYPES;
    float acc[8];
    #pragma unroll
    for (int j = 0; j < 8; ++j) acc[j] = 0.f;

    int e = o0;
    int pk0 = 0, pk1 = 0, pk2 = 0, pk3 = 0;
    bool run = (e + 16 <= o1);
    if (run) {
        pk0 = esrc[e + q];       pk1 = esrc[e + 4 + q];
        pk2 = esrc[e + 8 + q];   pk3 = esrc[e + 12 + q];
    }
    while (run) {
        uint4 r0 = *(const uint4*)(xwb7 + (size_t)(pk0 & 0xFFFFF) * C_DIM + l16 * 8);
        uint4 r1 = *(const uint4*)(xwb7 + (size_t)(pk1 & 0xFFFFF) * C_DIM + l16 * 8);
        uint4 r2 = *(const uint4*)(xwb7 + (size_t)(pk2 & 0xFFFFF) * C_DIM + l16 * 8);
        uint4 r3 = *(const uint4*)(xwb7 + (size_t)(pk3 & 0xFFFFF) * C_DIM + l16 * 8);
        float s0 = invd[pk0 >> 20];
        float s1 = invd[pk1 >> 20];
        float s2 = invd[pk2 >> 20];
        float s3 = invd[pk3 >> 20];
        e += 16;
        run = (e + 16 <= o1);
        if (run) {               // prefetch next iteration's packed indices
            pk0 = esrc[e + q];       pk1 = esrc[e + 4 + q];
            pk2 = esrc[e + 8 + q];   pk3 = esrc[e + 12 + q];
        }
        acc[0] += bf2f(r0.x & 0xffffu) * s0;  acc[1] += bf2f(r0.x >> 16) * s0;
        acc[2] += bf2f(r0.y & 0xffffu) * s0;  acc[3] += bf2f(r0.y >> 16) * s0;
        acc[4] += bf2f(r0.z & 0xffffu) * s0;  acc[5] += bf2f(r0.z >> 16) * s0;
        acc[6] += bf2f(r0.w & 0xffffu) * s0;  acc[7] += bf2f(r0.w >> 16) * s0;
        acc[0] += bf2f(r1.x & 0xffffu) * s1;  acc[1] += bf2f(r1.x >> 16) * s1;
        acc[2] += bf2f(r1.y & 0xffffu) * s1;  acc[3] += bf2f(r1.y >> 16) * s1;
        acc[4] += bf2f(r1.z & 0xffffu) * s1;  acc[5] += bf2f(r1.z >> 16) * s1;
        acc[6] += bf2f(r1.w & 0xffffu) * s1;  acc[7] += bf2f(r1.w >> 16) * s1;
        acc[0] += bf2f(r2.x & 0xffffu) * s2;  acc[1] += bf2f(r2.x >> 16) * s2;
        acc[2] += bf2f(r2.y & 0xffffu) * s2;  acc[3] += bf2f(r2.y >> 16) * s2;
        acc[4] += bf2f(r2.z & 0xffffu) * s2;  acc[5] += bf2f(r2.z >> 16) * s2;
        acc[6] += bf2f(r2.w & 0xffffu) * s2;  acc[7] += bf2f(r2.w >> 16) * s2;
        acc[0] += bf2f(r3.x & 0xffffu) * s3;  acc[1] += bf2f(r3.x >> 16) * s3;
        acc[2] += bf2f(r3.y & 0xffffu) * s3;  acc[3] += bf2f(r3.y >> 16) * s3;
        acc[4] += bf2f(r3.z & 0xffffu) * s3;  acc[5] += bf2f(r3.z >> 16) * s3;
        acc[6] += bf2f(r3.w & 0xffffu) * s3;  acc[7] += bf2f(r3.w >> 16) * s3;
    }
    // tail: 0-15 edges in up to 4 independent groups of 4 (uniform branches)
    #pragma unroll
    for (int j = 0; j < 4; ++j) {
        int eb = e + j * 4;
        if (eb < o1) {
            int idx = eb + q;
            bool valid = idx < o1;
            int pk = esrc[valid ? idx : eb];       // eb < o1: safe clamp
            uint4 rw = *(const uint4*)(xwb7 + (size_t)(pk & 0xFFFFF) * C_DIM + l16 * 8);
            float s = valid ? invd[pk >> 20] : 0.0f;
            acc[0] += bf2f(rw.x & 0xffffu) * s;  acc[1] += bf2f(rw.x >> 16) * s;
            acc[2] += bf2f(rw.y & 0xffffu) * s;  acc[3] += bf2f(rw.y >> 16) * s;
            acc[4] += bf2f(rw.z & 0xffffu) * s;  acc[5] += bf2f(rw.z >> 16) * s;
            acc[6] += bf2f(rw.w & 0xffffu) * s;  acc[7] += bf2f(rw.w >> 16) * s;
        }
    }

    #pragma unroll
    for (int j = 0; j < 8; ++j) {
        acc[j] += __shfl_xor(acc[j], 16);
        acc[j] += __shfl_xor(acc[j], 32);
    }
    if (lane < 32) {
        int fidx = (l16 << 1) | q;                 // q in {0,1} for lane<32
        float4 w = (lane < 16) ? make_float4(acc[0], acc[1], acc[2], acc[3])
                               : make_float4(acc[4], acc[5], acc[6], acc[7]);
        ((float4*)(out + (size_t)d * C_DIM))[fidx] = w;   // full overwrite
    }
}

// ---------------- fallback gather (single xwb plane, filter by r, RMW out) -----
__global__ void gather_rel_f(const int* __restrict__ dst_off, const int* __restrict__ esrc,
                             const float* __restrict__ inv,
                             const unsigned short* __restrict__ xwb,
                             float* __restrict__ out, int rf) {
    int wave = threadIdx.x >> 6, lane = threadIdx.x & 63;
    int d = blockIdx.x * 4 + wave;
    if (d >= N_NODES) return;
    int o0 = dst_off[d], o1 = dst_off[d + 1];
    float ax = 0.0f, ay = 0.0f;
    bool any = false;
    for (int e = o0; e < o1; ++e) {
        int pk = esrc[e];
        if ((pk >> 20) != rf) continue;
        any = true;
        int src = (pk & 0xFFFFF) - rf * XP_ROWS;
        unsigned int row = *(const unsigned int*)(xwb + (size_t)src * C_DIM + lane * 2);
        ax += bf2f(row & 0xffffu);
        ay += bf2f(row >> 16);
    }
    if (!any) return;
    float sc = inv[d * R_TYPES + rf];
    float2* po = (float2*)(out + (size_t)d * C_DIM) + lane;
    float2 v = *po;
    v.x += ax * sc;
    v.y += ay * sc;
    *po = v;
}

extern "C" void kernel_launch(void* const* d_in, const int* in_sizes, int n_in,
                              void* d_out, int out_size, void* d_ws, size_t ws_size,
                              hipStream_t stream) {
    const float* x      = (const float*)d_in[0];
    const int*   ei     = (const int*)d_in[1];
    const int*   et     = (const int*)d_in[2];
    const int*   tnt    = (const int*)d_in[3];
    const float* rel_w  = (const float*)d_in[4];
    const float* root_w = (const float*)d_in[5];
    const float* root_b = (const float*)d_in[6];
    float* out = (float*)d_out;

    char* ws = (char*)d_ws;
    int*   cnti    = (int*)(ws + OFF_CNTI);
    float* inv     = (float*)(ws + OFF_INV);
    int*   dst_off = (int*)(ws + OFF_DOFF);
    int*   cursor  = (int*)(ws + OFF_CURS);
    int*   bsum    = (int*)(ws + OFF_BSUM);
    int*   esrc    = (int*)(ws + OFF_ESRC);
    unsigned short* wf  = (unsigned short*)(ws + OFF_WF);
    unsigned short* xwb = (unsigned short*)(ws + OFF_XWB);
    unsigned short* wrf = (unsigned short*)(ws + OFF_WRF);   // in old perm region

    const bool full = (ws_size >= FULL_NEED);   // constant across calls: graph-safe

    hipMemsetAsync(ws + OFF_CNTI, 0, SEGS * sizeof(int), stream);
    if (!full)
        hipMemsetAsync(d_out, 0, (size_t)out_size * sizeof(float), stream);

    cvt_rootw_frag<<<32, 256, 0, stream>>>(root_w, wrf);

    // dst-CSR sort of edges
    edge_hist  <<<NB_E, 256, 0, stream>>>(ei, et, cnti);
    inv_kernel <<<(SEGS + 255) / 256, 256, 0, stream>>>(cnti, inv);
    dst_scan1  <<<NB_N, 256, 0, stream>>>(cnti, dst_off, bsum);
    seg_scan2  <<<1, 256, 0, stream>>>(bsum, NB_N);
    dst_scan3  <<<NB_N, 256, 0, stream>>>(dst_off, cursor, bsum);
    place_edges<<<NB_E * 8, 256, 0, stream>>>(ei, et, cursor, esrc);

    cvt_w_frag<<<56, 256, 0, stream>>>(rel_w, wf);

    if (full) {
        xw_gemm_all <<<XP_ROWS / 64, 256, 0, stream>>>(x, wf, xwb);
        gather_fused<<<(N_NODES + 3) / 4, 256, 0, stream>>>(dst_off, esrc, inv, xwb, out);
    } else {
        for (int r = 0; r < R_TYPES; ++r) {
            xw_gemm_mfma<<<XP_ROWS / 128, 256, 0, stream>>>(x, wf, xwb, r);
            gather_rel_f<<<(N_NODES + 3) / 4, 256, 0, stream>>>(dst_off, esrc, inv, xwb, out, r);
        }
    }
    // root linear last: RMW onto gather's output
    root_nat<<<NB_ROOT, 256, 0, stream>>>(x, wrf, root_b, tnt, out);
}

// Round 10
// 468.625 us; speedup vs baseline: 1.0398x; 1.0398x over previous
//
#include <hip/hip_runtime.h>

#define N_NODES 100000
#define N_EDGES 1600000
#define C_DIM   128
#define R_TYPES 7
#define T_TYPES 4
#define SEGS    (N_NODES * R_TYPES)          // 700000 (dst,rel) segments
#define NB_E    (N_EDGES / 256)              // 6250 (E % 256 == 0)
#define NB_N    ((N_NODES + 255) / 256)      // 391 node blocks (also dst-scan blocks)
#define XP_ROWS 100096                       // N padded: /64 = 1564 exact, /128 = 782
#define DST_PART 12500                       // N / 8 (exact)
#define NB_ROOT ((N_NODES + 63) / 64)        // 1563 root blocks (64 nodes each)

// ---- workspace layout (bytes) ----
#define OFF_CNTI   0ull                       // int  cnti[SEGS]            2.80 MB
#define OFF_INV    2800000ull                 // f32  inv[SEGS]             2.80 MB
#define OFF_DOFF   5600000ull                 // int  dst_off[N+1]          0.40 MB
#define OFF_CURS   6000004ull                 // int  cursor[N]             0.40 MB
#define OFF_MISC   6400004ull                 // int  misc[32]   (unused now)
#define OFF_PERM   6400132ull                 // REUSED: bf16 wrf[8*16384] = 256 KB
#define PERM_CAP   100288
#define OFF_BLKN   6801284ull                 // (unused now)
#define OFF_BSUM   6813796ull                 // int  bsum[NB_N]
#define OFF_ESRC   6815360ull                 // int  esrc[E] packed r<<20|(r*XP_ROWS+src)
#define OFF_XP     13215360ull                // (unused now -- GEMM reads x directly)
#define OFF_WF     38839936ull                // bf16 wf[7*128*128] frag        0.23 MB
#define OFF_XWB    39069312ull                // bf16 xwb: full = 7 planes, fallback = 1
#define XWB_PLANE  ((size_t)XP_ROWS * 128)    // elements per relation plane
#define FULL_NEED  218441344ull               // OFF_XWB + 7*25,624,576
#define FB_NEED    64693888ull                // OFF_XWB + 1*25,624,576
#define OFF_WRF    OFF_PERM                   // root hi/lo W frags (256 KB)

typedef __attribute__((ext_vector_type(8))) short short8;
typedef __attribute__((ext_vector_type(4))) float f32x4;

__device__ inline unsigned short f2bf(float f) {
    unsigned int u = __float_as_uint(f);
    u += 0x7fffu + ((u >> 16) & 1u);          // RNE
    return (unsigned short)(u >> 16);
}
__device__ inline float bf2f(unsigned int h) { return __uint_as_float(h << 16); }

// ---------------- per-(dst,rel) counts ----------------
__global__ void edge_hist(const int* __restrict__ ei, const int* __restrict__ et,
                          int* __restrict__ cnti) {
    int e = blockIdx.x * 256 + threadIdx.x;
    atomicAdd(&cnti[ei[N_EDGES + e] * R_TYPES + et[e]], 1);   // 700k addrs: low contention
}

__global__ void inv_kernel(const int* __restrict__ cnti, float* __restrict__ inv) {
    int i = blockIdx.x * blockDim.x + threadIdx.x;
    if (i < SEGS) inv[i] = 1.0f / (float)max(cnti[i], 1);
}

// ---------------- dst-CSR: dst_off = exclusive scan of per-dst degree ----------------
__global__ void dst_scan1(const int* __restrict__ cnti, int* __restrict__ dst_off,
                          int* __restrict__ bsum) {
    __shared__ int sbuf[256];
    int tid = threadIdx.x;
    int i = blockIdx.x * 256 + tid;
    int v = 0;
    if (i < N_NODES) {
        #pragma unroll
        for (int r = 0; r < R_TYPES; ++r) v += cnti[i * R_TYPES + r];
    }
    sbuf[tid] = v;
    __syncthreads();
    #pragma unroll
    for (int off = 1; off < 256; off <<= 1) {
        int t = (tid >= off) ? sbuf[tid - off] : 0;
        __syncthreads();
        sbuf[tid] += t;
        __syncthreads();
    }
    int incl = sbuf[tid];
    if (i < N_NODES) dst_off[i] = incl - v;   // exclusive within chunk
    if (tid == 255) bsum[blockIdx.x] = incl;
}

__global__ void seg_scan2(int* __restrict__ bsum, int nb) {   // 1 block
    __shared__ int sbuf[256];
    int tid = threadIdx.x;
    int running = 0;
    for (int c0 = 0; c0 < nb; c0 += 256) {
        int b = c0 + tid;
        int v = (b < nb) ? bsum[b] : 0;
        sbuf[tid] = v;
        __syncthreads();
        #pragma unroll
        for (int off = 1; off < 256; off <<= 1) {
            int t = (tid >= off) ? sbuf[tid - off] : 0;
            __syncthreads();
            sbuf[tid] += t;
            __syncthreads();
        }
        int incl = sbuf[tid];
        int tot = sbuf[255];
        __syncthreads();
        if (b < nb) bsum[b] = running + incl - v;
        running += tot;
    }
}

__global__ void dst_scan3(int* __restrict__ dst_off, int* __restrict__ cursor,
                          const int* __restrict__ bsum) {
    int i = blockIdx.x * 256 + threadIdx.x;
    if (i < N_NODES) {
        int val = dst_off[i] + bsum[blockIdx.x];
        dst_off[i] = val;
        cursor[i] = val;
    }
    if (i == 0) dst_off[N_NODES] = N_EDGES;
}

// XCD-partitioned placement: block b = chunk (b>>3) x partition (b&7).
__global__ void place_edges(const int* __restrict__ ei, const int* __restrict__ et,
                            int* __restrict__ cursor, int* __restrict__ esrc) {
    int p = blockIdx.x & 7;
    int e = (blockIdx.x >> 3) * 256 + threadIdx.x;
    int d = ei[N_EDGES + e];
    if (d / DST_PART != p) return;
    int pos = atomicAdd(&cursor[d], 1);
    int r = et[e];
    esrc[pos] = (r << 20) | (r * XP_ROWS + ei[e]);   // r in [20:23), rowidx in [0:20)
}

// ---------------- bf16 fragment-layout conversions ----------------
__global__ void cvt_w_frag(const float* __restrict__ rel_w, unsigned short* __restrict__ wf) {
    int id = blockIdx.x * 256 + threadIdx.x;       // 7*128*16 = 14336 exact
    if (id >= R_TYPES * 128 * 16) return;
    int r = id >> 11, rest = id & 2047;
    int o = rest >> 4, ko = rest & 15;
    const float4* pw = (const float4*)(rel_w + (size_t)r * 16384 + o * 128 + ko * 8);
    float4 a = pw[0], b = pw[1];
    short8 v;
    v[0] = (short)f2bf(a.x); v[1] = (short)f2bf(a.y);
    v[2] = (short)f2bf(a.z); v[3] = (short)f2bf(a.w);
    v[4] = (short)f2bf(b.x); v[5] = (short)f2bf(b.y);
    v[6] = (short)f2bf(b.z); v[7] = (short)f2bf(b.w);
    size_t off = (size_t)r * 16384 + (o >> 4) * 2048 + (ko >> 2) * 512 + (ko & 3) * 128 + (o & 15) * 8;
    *(short8*)(wf + off) = v;
}

// root_w -> MFMA B-frag layout, hi plane [0..3] and lo plane [4..7] (hi/lo bf16 split)
__global__ void cvt_rootw_frag(const float* __restrict__ root_w, unsigned short* __restrict__ wrf) {
    int id = blockIdx.x * 256 + threadIdx.x;       // 4*128*16 = 8192 exact
    if (id >= T_TYPES * 128 * 16) return;
    int t = id >> 11, rest = id & 2047;
    int o = rest >> 4, ko = rest & 15;
    const float4* pw = (const float4*)(root_w + (size_t)t * 16384 + o * 128 + ko * 8);
    float4 a = pw[0], b = pw[1];
    float v[8] = {a.x, a.y, a.z, a.w, b.x, b.y, b.z, b.w};
    short8 hi, lo;
    #pragma unroll
    for (int j = 0; j < 8; ++j) {
        unsigned short h = f2bf(v[j]);
        hi[j] = (short)h;
        lo[j] = (short)f2bf(v[j] - bf2f(h));
    }
    size_t off = (size_t)t * 16384 + (o >> 4) * 2048 + (ko >> 2) * 512 + (ko & 3) * 128 + (o & 15) * 8;
    *(short8*)(wrf + off) = hi;
    *(short8*)(wrf + (size_t)T_TYPES * 16384 + off) = lo;
}

// ---------------- root linear, NATURAL node order + local type grouping ----------
// Runs LAST (RMW onto gather's output). ILP-restructured (R7, best measured):
// RMW loads first, 8 parallel ct accumulator chains, store-only epilogue.
__launch_bounds__(256)
__global__ void root_nat(const float* __restrict__ x, const unsigned short* __restrict__ wrf,
                         const float* __restrict__ root_b, const int* __restrict__ tnt,
                         float* __restrict__ out) {
    __shared__ int cnt[T_TYPES];
    __shared__ int goff[T_TYPES];
    __shared__ int rankb[64];
    __shared__ int lidx[112];          // 7 tiles x 16 rows max
    __shared__ int ttyp[8];
    __shared__ int ntile_s;
    int tid = threadIdx.x;
    int base = blockIdx.x * 64;
    if (tid < T_TYPES) cnt[tid] = 0;
    if (tid < 112) lidx[tid] = -1;
    __syncthreads();
    int myt = -1;
    if (tid < 64 && base + tid < N_NODES) {
        myt = tnt[base + tid];
        rankb[tid] = atomicAdd(&cnt[myt], 1);
    }
    __syncthreads();
    if (tid == 0) {
        int s = 0;
        for (int t = 0; t < T_TYPES; ++t) {
            goff[t] = s;
            int nt = (cnt[t] + 15) >> 4;
            for (int k = 0; k < nt; ++k) ttyp[(s >> 4) + k] = t;
            s += nt << 4;
        }
        ntile_s = s >> 4;
    }
    __syncthreads();
    if (myt >= 0) lidx[goff[myt] + rankb[tid]] = base + tid;
    __syncthreads();
    int ntiles = ntile_s;

    int wave = tid >> 6, lane = tid & 63;
    int l16 = lane & 15, kq = lane >> 4;
    for (int tile = wave; tile < ntiles; tile += 4) {
        int t = ttyp[tile];

        int nr0 = lidx[tile * 16 + kq * 4 + 0];
        int nr1 = lidx[tile * 16 + kq * 4 + 1];
        int nr2 = lidx[tile * 16 + kq * 4 + 2];
        int nr3 = lidx[tile * 16 + kq * 4 + 3];

        float ov[8][4];
        #pragma unroll
        for (int ct = 0; ct < 8; ++ct) {
            ov[ct][0] = (nr0 >= 0) ? out[(size_t)nr0 * C_DIM + ct * 16 + l16] : 0.0f;
            ov[ct][1] = (nr1 >= 0) ? out[(size_t)nr1 * C_DIM + ct * 16 + l16] : 0.0f;
            ov[ct][2] = (nr2 >= 0) ? out[(size_t)nr2 * C_DIM + ct * 16 + l16] : 0.0f;
            ov[ct][3] = (nr3 >= 0) ? out[(size_t)nr3 * C_DIM + ct * 16 + l16] : 0.0f;
        }
        float bias[8];
        #pragma unroll
        for (int ct = 0; ct < 8; ++ct) bias[ct] = root_b[t * 128 + ct * 16 + l16];

        int node = lidx[tile * 16 + l16];
        short8 ah[4], al[4];
        #pragma unroll
        for (int kb = 0; kb < 4; ++kb) {
            float v[8];
            if (node >= 0) {
                const float4* px = (const float4*)(x + (size_t)node * C_DIM + kb * 32 + kq * 8);
                float4 p0 = px[0], p1 = px[1];
                v[0] = p0.x; v[1] = p0.y; v[2] = p0.z; v[3] = p0.w;
                v[4] = p1.x; v[5] = p1.y; v[6] = p1.z; v[7] = p1.w;
            } else {
                #pragma unroll
                for (int j = 0; j < 8; ++j) v[j] = 0.0f;
            }
            #pragma unroll
            for (int j = 0; j < 8; ++j) {
                unsigned short h = f2bf(v[j]);
                ah[kb][j] = (short)h;
                al[kb][j] = (short)f2bf(v[j] - bf2f(h));
            }
        }

        const unsigned short* wh = wrf + (size_t)t * 16384;
        const unsigned short* wl = wh + (size_t)T_TYPES * 16384;
        f32x4 acc[8];
        #pragma unroll
        for (int ct = 0; ct < 8; ++ct) acc[ct] = (f32x4)0.0f;
        #pragma unroll
        for (int kb = 0; kb < 4; ++kb) {
            #pragma unroll
            for (int ct = 0; ct < 8; ++ct) {
                short8 bh = *(const short8*)(wh + ct * 2048 + kb * 512 + lane * 8);
                short8 bl = *(const short8*)(wl + ct * 2048 + kb * 512 + lane * 8);
                acc[ct] = __builtin_amdgcn_mfma_f32_16x16x32_bf16(ah[kb], bh, acc[ct], 0, 0, 0);
                acc[ct] = __builtin_amdgcn_mfma_f32_16x16x32_bf16(al[kb], bh, acc[ct], 0, 0, 0);
                acc[ct] = __builtin_amdgcn_mfma_f32_16x16x32_bf16(ah[kb], bl, acc[ct], 0, 0, 0);
            }
        }

        #pragma unroll
        for (int ct = 0; ct < 8; ++ct) {
            if (nr0 >= 0) out[(size_t)nr0 * C_DIM + ct * 16 + l16] = ov[ct][0] + acc[ct][0] + bias[ct];
            if (nr1 >= 0) out[(size_t)nr1 * C_DIM + ct * 16 + l16] = ov[ct][1] + acc[ct][1] + bias[ct];
            if (nr2 >= 0) out[(size_t)nr2 * C_DIM + ct * 16 + l16] = ov[ct][2] + acc[ct][2] + bias[ct];
            if (nr3 >= 0) out[(size_t)nr3 * C_DIM + ct * 16 + l16] = ov[ct][3] + acc[ct][3] + bias[ct];
        }
    }
}

// ---------------- fused MFMA GEMM, all 7 relations, 64-row blocks ---------------
// R7 store orientation (best measured: 16 lanes = 16 consecutive channels of one
// row, 32B segments) with HALVED tile: grid 1564 -> ~6 blocks/CU, occupancy
// ~70% (was 30% at 782 blocks) to hide store latency. Stores unconditional:
// pad rows (N_NODES..XP_ROWS) are written but never read by gather.
__launch_bounds__(256)
__global__ void xw_gemm_all(const float* __restrict__ x,
                            const unsigned short* __restrict__ wf,
                            unsigned short* __restrict__ xwb7) {
    int wave = threadIdx.x >> 6, lane = threadIdx.x & 63;
    int m0 = blockIdx.x * 64;
    int l16 = lane & 15, kq = lane >> 4;

    int row = m0 + wave * 16 + l16;
    bool ok = row < N_NODES;
    short8 a[4];
    #pragma unroll
    for (int kb = 0; kb < 4; ++kb) {
        float v[8];
        if (ok) {
            const float4* px = (const float4*)(x + (size_t)row * C_DIM + kb * 32 + kq * 8);
            float4 p0 = px[0], p1 = px[1];
            v[0] = p0.x; v[1] = p0.y; v[2] = p0.z; v[3] = p0.w;
            v[4] = p1.x; v[5] = p1.y; v[6] = p1.z; v[7] = p1.w;
        } else {
            #pragma unroll
            for (int j = 0; j < 8; ++j) v[j] = 0.0f;
        }
        #pragma unroll
        for (int j = 0; j < 8; ++j) a[kb][j] = (short)f2bf(v[j]);
    }

    int col = l16, rq = kq * 4;                    // C/D: col=lane&15,row=(lane>>4)*4+i
    size_t base = (size_t)(m0 + wave * 16 + rq) * C_DIM + col;
    for (int r = 0; r < R_TYPES; ++r) {
        const unsigned short* wr = wf + (size_t)r * 16384;
        unsigned short* xwb = xwb7 + (size_t)r * XWB_PLANE;
        #pragma unroll
        for (int ct = 0; ct < 8; ++ct) {
            f32x4 acc = (f32x4)0.0f;
            #pragma unroll
            for (int kb = 0; kb < 4; ++kb) {
                short8 b = *(const short8*)(wr + (size_t)ct * 2048 + kb * 512 + lane * 8);
                acc = __builtin_amdgcn_mfma_f32_16x16x32_bf16(a[kb], b, acc, 0, 0, 0);
            }
            #pragma unroll
            for (int i = 0; i < 4; ++i)
                xwb[base + (size_t)i * C_DIM + ct * 16] = f2bf(acc[i]);   // unconditional
        }
    }
}

// fallback per-relation GEMM (single plane), A read directly from x (128-row blocks)
__launch_bounds__(256)
__global__ void xw_gemm_mfma(const float* __restrict__ x,
                             const unsigned short* __restrict__ wf,
                             unsigned short* __restrict__ xwb, int r) {
    int wave = threadIdx.x >> 6, lane = threadIdx.x & 63;
    int m0 = blockIdx.x * 128;
    int l16 = lane & 15, kq = lane >> 4;
    const unsigned short* wr = wf + (size_t)r * 16384;

    short8 a[4][2];
    #pragma unroll
    for (int rt = 0; rt < 2; ++rt) {
        int row = m0 + wave * 32 + rt * 16 + l16;
        bool ok = row < N_NODES;
        #pragma unroll
        for (int kb = 0; kb < 4; ++kb) {
            float v[8];
            if (ok) {
                const float4* px = (const float4*)(x + (size_t)row * C_DIM + kb * 32 + kq * 8);
                float4 p0 = px[0], p1 = px[1];
                v[0] = p0.x; v[1] = p0.y; v[2] = p0.z; v[3] = p0.w;
                v[4] = p1.x; v[5] = p1.y; v[6] = p1.z; v[7] = p1.w;
            } else {
                #pragma unroll
                for (int j = 0; j < 8; ++j) v[j] = 0.0f;
            }
            #pragma unroll
            for (int j = 0; j < 8; ++j) a[kb][rt][j] = (short)f2bf(v[j]);
        }
    }

    int col = l16, rq = kq * 4;
    #pragma unroll
    for (int ct = 0; ct < 8; ++ct) {
        f32x4 acc0 = (f32x4)0.0f, acc1 = (f32x4)0.0f;
        #pragma unroll
        for (int kb = 0; kb < 4; ++kb) {
            short8 b = *(const short8*)(wr + (size_t)ct * 2048 + kb * 512 + lane * 8);
            acc0 = __builtin_amdgcn_mfma_f32_16x16x32_bf16(a[kb][0], b, acc0, 0, 0, 0);
            acc1 = __builtin_amdgcn_mfma_f32_16x16x32_bf16(a[kb][1], b, acc1, 0, 0, 0);
        }
        #pragma unroll
        for (int i = 0; i < 4; ++i) {
            int n0 = m0 + wave * 32 + rq + i;
            if (n0 < N_NODES)
                xwb[(size_t)n0 * C_DIM + ct * 16 + col] = f2bf(acc0[i]);
            int n1 = n0 + 16;
            if (n1 < N_NODES)
                xwb[(size_t)n1 * C_DIM + ct * 16 + col] = f2bf(acc1[i]);
        }
    }
}

// ---------------- fused gather: out[d] = sum over d's edges of xwb7[r][src]*inv
// 16 edges per main iteration: 4 independent uint4 row loads in flight per wave
// (quarter-lane layout: 16 lanes x 16B per row). esrc prefetched one iteration
// ahead. Tail issues its group loads independently. Pure overwrite.
__global__ void gather_fused(const int* __restrict__ dst_off, const int* __restrict__ esrc,
                             const float* __restrict__ inv,
                             const unsigned short* __restrict__ xwb7,
                             float* __restrict__ out) {
    int wave = threadIdx.x >> 6, lane = threadIdx.x & 63;
    int d = blockIdx.x * 4 + wave;
    if (d >= N_NODES) return;
    int o0 = dst_off[d], o1 = dst_off[d + 1];
    int q = lane >> 4;               // quarter: which edge of a 4-group
    int l16 = lane & 15;
    const float* invd = inv + d * R_TYPES;
    float acc[8];
    #pragma unroll
    for (int j = 0; j < 8; ++j) acc[j] = 0.f;

    int e = o0;
    int pk0 = 0, pk1 = 0, pk2 = 0, pk3 = 0;
    bool run = (e + 16 <= o1);
    if (run) {
        pk0 = esrc[e + q];       pk1 = esrc[e + 4 + q];
        pk2 = esrc[e + 8 + q];   pk3 = esrc[e + 12 + q];
    }
    while (run) {
        uint4 r0 = *(const uint4*)(xwb7 + (size_t)(pk0 & 0xFFFFF) * C_DIM + l16 * 8);
        uint4 r1 = *(const uint4*)(xwb7 + (size_t)(pk1 & 0xFFFFF) * C_DIM + l16 * 8);
        uint4 r2 = *(const uint4*)(xwb7 + (size_t)(pk2 & 0xFFFFF) * C_DIM + l16 * 8);
        uint4 r3 = *(const uint4*)(xwb7 + (size_t)(pk3 & 0xFFFFF) * C_DIM + l16 * 8);
        float s0 = invd[pk0 >> 20];
        float s1 = invd[pk1 >> 20];
        float s2 = invd[pk2 >> 20];
        float s3 = invd[pk3 >> 20];
        e += 16;
        run = (e + 16 <= o1);
        if (run) {               // prefetch next iteration's packed indices
            pk0 = esrc[e + q];       pk1 = esrc[e + 4 + q];
            pk2 = esrc[e + 8 + q];   pk3 = esrc[e + 12 + q];
        }
        acc[0] += bf2f(r0.x & 0xffffu) * s0;  acc[1] += bf2f(r0.x >> 16) * s0;
        acc[2] += bf2f(r0.y & 0xffffu) * s0;  acc[3] += bf2f(r0.y >> 16) * s0;
        acc[4] += bf2f(r0.z & 0xffffu) * s0;  acc[5] += bf2f(r0.z >> 16) * s0;
        acc[6] += bf2f(r0.w & 0xffffu) * s0;  acc[7] += bf2f(r0.w >> 16) * s0;
        acc[0] += bf2f(r1.x & 0xffffu) * s1;  acc[1] += bf2f(r1.x >> 16) * s1;
        acc[2] += bf2f(r1.y & 0xffffu) * s1;  acc[3] += bf2f(r1.y >> 16) * s1;
        acc[4] += bf2f(r1.z & 0xffffu) * s1;  acc[5] += bf2f(r1.z >> 16) * s1;
        acc[6] += bf2f(r1.w & 0xffffu) * s1;  acc[7] += bf2f(r1.w >> 16) * s1;
        acc[0] += bf2f(r2.x & 0xffffu) * s2;  acc[1] += bf2f(r2.x >> 16) * s2;
        acc[2] += bf2f(r2.y & 0xffffu) * s2;  acc[3] += bf2f(r2.y >> 16) * s2;
        acc[4] += bf2f(r2.z & 0xffffu) * s2;  acc[5] += bf2f(r2.z >> 16) * s2;
        acc[6] += bf2f(r2.w & 0xffffu) * s2;  acc[7] += bf2f(r2.w >> 16) * s2;
        acc[0] += bf2f(r3.x & 0xffffu) * s3;  acc[1] += bf2f(r3.x >> 16) * s3;
        acc[2] += bf2f(r3.y & 0xffffu) * s3;  acc[3] += bf2f(r3.y >> 16) * s3;
        acc[4] += bf2f(r3.z & 0xffffu) * s3;  acc[5] += bf2f(r3.z >> 16) * s3;
        acc[6] += bf2f(r3.w & 0xffffu) * s3;  acc[7] += bf2f(r3.w >> 16) * s3;
    }
    // tail: 0-15 edges in up to 4 independent groups of 4 (uniform branches)
    #pragma unroll
    for (int j = 0; j < 4; ++j) {
        int eb = e + j * 4;
        if (eb < o1) {
            int idx = eb + q;
            bool valid = idx < o1;
            int pk = esrc[valid ? idx : eb];       // eb < o1: safe clamp
            uint4 rw = *(const uint4*)(xwb7 + (size_t)(pk & 0xFFFFF) * C_DIM + l16 * 8);
            float s = valid ? invd[pk >> 20] : 0.0f;
            acc[0] += bf2f(rw.x & 0xffffu) * s;  acc[1] += bf2f(rw.x >> 16) * s;
            acc[2] += bf2f(rw.y & 0xffffu) * s;  acc[3] += bf2f(rw.y >> 16) * s;
            acc[4] += bf2f(rw.z & 0xffffu) * s;  acc[5] += bf2f(rw.z >> 16) * s;
            acc[6] += bf2f(rw.w & 0xffffu) * s;  acc[7] += bf2f(rw.w >> 16) * s;
        }
    }

    #pragma unroll
    for (int j = 0; j < 8; ++j) {
        acc[j] += __shfl_xor(acc[j], 16);
        acc[j] += __shfl_xor(acc[j], 32);
    }
    if (lane < 32) {
        int fidx = (l16 << 1) | q;                 // q in {0,1} for lane<32
        float4 w = (lane < 16) ? make_float4(acc[0], acc[1], acc[2], acc[3])
                               : make_float4(acc[4], acc[5], acc[6], acc[7]);
        ((float4*)(out + (size_t)d * C_DIM))[fidx] = w;   // full overwrite
    }
}

// ---------------- fallback gather (single xwb plane, filter by r, RMW out) -----
__global__ void gather_rel_f(const int* __restrict__ dst_off, const int* __restrict__ esrc,
                             const float* __restrict__ inv,
                             const unsigned short* __restrict__ xwb,
                             float* __restrict__ out, int rf) {
    int wave = threadIdx.x >> 6, lane = threadIdx.x & 63;
    int d = blockIdx.x * 4 + wave;
    if (d >= N_NODES) return;
    int o0 = dst_off[d], o1 = dst_off[d + 1];
    float ax = 0.0f, ay = 0.0f;
    bool any = false;
    for (int e = o0; e < o1; ++e) {
        int pk = esrc[e];
        if ((pk >> 20) != rf) continue;
        any = true;
        int src = (pk & 0xFFFFF) - rf * XP_ROWS;
        unsigned int row = *(const unsigned int*)(xwb + (size_t)src * C_DIM + lane * 2);
        ax += bf2f(row & 0xffffu);
        ay += bf2f(row >> 16);
    }
    if (!any) return;
    float sc = inv[d * R_TYPES + rf];
    float2* po = (float2*)(out + (size_t)d * C_DIM) + lane;
    float2 v = *po;
    v.x += ax * sc;
    v.y += ay * sc;
    *po = v;
}

extern "C" void kernel_launch(void* const* d_in, const int* in_sizes, int n_in,
                              void* d_out, int out_size, void* d_ws, size_t ws_size,
                              hipStream_t stream) {
    const float* x      = (const float*)d_in[0];
    const int*   ei     = (const int*)d_in[1];
    const int*   et     = (const int*)d_in[2];
    const int*   tnt    = (const int*)d_in[3];
    const float* rel_w  = (const float*)d_in[4];
    const float* root_w = (const float*)d_in[5];
    const float* root_b = (const float*)d_in[6];
    float* out = (float*)d_out;

    char* ws = (char*)d_ws;
    int*   cnti    = (int*)(ws + OFF_CNTI);
    float* inv     = (float*)(ws + OFF_INV);
    int*   dst_off = (int*)(ws + OFF_DOFF);
    int*   cursor  = (int*)(ws + OFF_CURS);
    int*   bsum    = (int*)(ws + OFF_BSUM);
    int*   esrc    = (int*)(ws + OFF_ESRC);
    unsigned short* wf  = (unsigned short*)(ws + OFF_WF);
    unsigned short* xwb = (unsigned short*)(ws + OFF_XWB);
    unsigned short* wrf = (unsigned short*)(ws + OFF_WRF);   // in old perm region

    const bool full = (ws_size >= FULL_NEED);   // constant across calls: graph-safe

    hipMemsetAsync(ws + OFF_CNTI, 0, SEGS * sizeof(int), stream);
    if (!full)
        hipMemsetAsync(d_out, 0, (size_t)out_size * sizeof(float), stream);

    cvt_rootw_frag<<<32, 256, 0, stream>>>(root_w, wrf);

    // dst-CSR sort of edges
    edge_hist  <<<NB_E, 256, 0, stream>>>(ei, et, cnti);
    inv_kernel <<<(SEGS + 255) / 256, 256, 0, stream>>>(cnti, inv);
    dst_scan1  <<<NB_N, 256, 0, stream>>>(cnti, dst_off, bsum);
    seg_scan2  <<<1, 256, 0, stream>>>(bsum, NB_N);
    dst_scan3  <<<NB_N, 256, 0, stream>>>(dst_off, cursor, bsum);
    place_edges<<<NB_E * 8, 256, 0, stream>>>(ei, et, cursor, esrc);

    cvt_w_frag<<<56, 256, 0, stream>>>(rel_w, wf);

    if (full) {
        xw_gemm_all <<<XP_ROWS / 64, 256, 0, stream>>>(x, wf, xwb);
        gather_fused<<<(N_NODES + 3) / 4, 256, 0, stream>>>(dst_off, esrc, inv, xwb, out);
    } else {
        for (int r = 0; r < R_TYPES; ++r) {
            xw_gemm_mfma<<<XP_ROWS / 128, 256, 0, stream>>>(x, wf, xwb, r);
            gather_rel_f<<<(N_NODES + 3) / 4, 256, 0, stream>>>(dst_off, esrc, inv, xwb, out, r);
        }
    }
    // root linear last: RMW onto gather's output
    root_nat<<<NB_ROOT, 256, 0, stream>>>(x, wrf, root_b, tnt, out);
}

// Round 11
// 451.373 us; speedup vs baseline: 1.0795x; 1.0382x over previous
//
#include <hip/hip_runtime.h>

#define N_NODES 100000
#define N_EDGES 1600000
#define C_DIM   128
#define R_TYPES 7
#define T_TYPES 4
#define SEGS    (N_NODES * R_TYPES)          // 700000 (dst,rel) segments
#define NB_E    (N_EDGES / 256)              // 6250 (E % 256 == 0)
#define NB_N    ((N_NODES + 255) / 256)      // 391 node blocks (also dst-scan blocks)
#define XP_ROWS 100096                       // N padded: /64 = 1564 exact, /128 = 782
#define DST_PART 12500                       // N / 8 (exact)
#define NB_ROOT ((N_NODES + 63) / 64)        // 1563 root blocks (64 nodes each)

// ---- workspace layout (bytes) ----
#define OFF_CNTI   0ull                       // int  cnti[SEGS]            2.80 MB
#define OFF_INV    2800000ull                 // f32  inv[SEGS]             2.80 MB
#define OFF_DOFF   5600000ull                 // int  dst_off[N+1]          0.40 MB
#define OFF_CURS   6000004ull                 // int  cursor[N]             0.40 MB
#define OFF_MISC   6400004ull                 // int  misc[32]   (unused now)
#define OFF_PERM   6400132ull                 // REUSED: bf16 wrf[8*16384] = 256 KB
#define PERM_CAP   100288
#define OFF_BLKN   6801284ull                 // (unused now)
#define OFF_BSUM   6813796ull                 // int  bsum[NB_N]
#define OFF_ESRC   6815360ull                 // int  esrc[E] packed r<<20|(r*XP_ROWS+src)
#define OFF_XP     13215360ull                // (unused now -- GEMM reads x directly)
#define OFF_WF     38839936ull                // bf16 wf[7*128*128] frag        0.23 MB
#define OFF_XWB    39069312ull                // bf16 xwb: full = 7 planes, fallback = 1
#define XWB_PLANE  ((size_t)XP_ROWS * 128)    // elements per relation plane
#define FULL_NEED  218441344ull               // OFF_XWB + 7*25,624,576
#define FB_NEED    64693888ull                // OFF_XWB + 1*25,624,576
#define OFF_WRF    OFF_PERM                   // root hi/lo W frags (256 KB)

typedef __attribute__((ext_vector_type(8))) short short8;
typedef __attribute__((ext_vector_type(4))) float f32x4;

__device__ inline unsigned short f2bf(float f) {
    unsigned int u = __float_as_uint(f);
    u += 0x7fffu + ((u >> 16) & 1u);          // RNE
    return (unsigned short)(u >> 16);
}
__device__ inline float bf2f(unsigned int h) { return __uint_as_float(h << 16); }

// ---------------- per-(dst,rel) counts ----------------
__global__ void edge_hist(const int* __restrict__ ei, const int* __restrict__ et,
                          int* __restrict__ cnti) {
    int e = blockIdx.x * 256 + threadIdx.x;
    atomicAdd(&cnti[ei[N_EDGES + e] * R_TYPES + et[e]], 1);   // 700k addrs: low contention
}

__global__ void inv_kernel(const int* __restrict__ cnti, float* __restrict__ inv) {
    int i = blockIdx.x * blockDim.x + threadIdx.x;
    if (i < SEGS) inv[i] = 1.0f / (float)max(cnti[i], 1);
}

// ---------------- dst-CSR: dst_off = exclusive scan of per-dst degree ----------------
__global__ void dst_scan1(const int* __restrict__ cnti, int* __restrict__ dst_off,
                          int* __restrict__ bsum) {
    __shared__ int sbuf[256];
    int tid = threadIdx.x;
    int i = blockIdx.x * 256 + tid;
    int v = 0;
    if (i < N_NODES) {
        #pragma unroll
        for (int r = 0; r < R_TYPES; ++r) v += cnti[i * R_TYPES + r];
    }
    sbuf[tid] = v;
    __syncthreads();
    #pragma unroll
    for (int off = 1; off < 256; off <<= 1) {
        int t = (tid >= off) ? sbuf[tid - off] : 0;
        __syncthreads();
        sbuf[tid] += t;
        __syncthreads();
    }
    int incl = sbuf[tid];
    if (i < N_NODES) dst_off[i] = incl - v;   // exclusive within chunk
    if (tid == 255) bsum[blockIdx.x] = incl;
}

__global__ void seg_scan2(int* __restrict__ bsum, int nb) {   // 1 block
    __shared__ int sbuf[256];
    int tid = threadIdx.x;
    int running = 0;
    for (int c0 = 0; c0 < nb; c0 += 256) {
        int b = c0 + tid;
        int v = (b < nb) ? bsum[b] : 0;
        sbuf[tid] = v;
        __syncthreads();
        #pragma unroll
        for (int off = 1; off < 256; off <<= 1) {
            int t = (tid >= off) ? sbuf[tid - off] : 0;
            __syncthreads();
            sbuf[tid] += t;
            __syncthreads();
        }
        int incl = sbuf[tid];
        int tot = sbuf[255];
        __syncthreads();
        if (b < nb) bsum[b] = running + incl - v;
        running += tot;
    }
}

__global__ void dst_scan3(int* __restrict__ dst_off, int* __restrict__ cursor,
                          const int* __restrict__ bsum) {
    int i = blockIdx.x * 256 + threadIdx.x;
    if (i < N_NODES) {
        int val = dst_off[i] + bsum[blockIdx.x];
        dst_off[i] = val;
        cursor[i] = val;
    }
    if (i == 0) dst_off[N_NODES] = N_EDGES;
}

// XCD-partitioned placement: block b = chunk (b>>3) x partition (b&7).
__global__ void place_edges(const int* __restrict__ ei, const int* __restrict__ et,
                            int* __restrict__ cursor, int* __restrict__ esrc) {
    int p = blockIdx.x & 7;
    int e = (blockIdx.x >> 3) * 256 + threadIdx.x;
    int d = ei[N_EDGES + e];
    if (d / DST_PART != p) return;
    int pos = atomicAdd(&cursor[d], 1);
    int r = et[e];
    esrc[pos] = (r << 20) | (r * XP_ROWS + ei[e]);   // r in [20:23), rowidx in [0:20)
}

// ---------------- bf16 fragment-layout conversions ----------------
__global__ void cvt_w_frag(const float* __restrict__ rel_w, unsigned short* __restrict__ wf) {
    int id = blockIdx.x * 256 + threadIdx.x;       // 7*128*16 = 14336 exact
    if (id >= R_TYPES * 128 * 16) return;
    int r = id >> 11, rest = id & 2047;
    int o = rest >> 4, ko = rest & 15;
    const float4* pw = (const float4*)(rel_w + (size_t)r * 16384 + o * 128 + ko * 8);
    float4 a = pw[0], b = pw[1];
    short8 v;
    v[0] = (short)f2bf(a.x); v[1] = (short)f2bf(a.y);
    v[2] = (short)f2bf(a.z); v[3] = (short)f2bf(a.w);
    v[4] = (short)f2bf(b.x); v[5] = (short)f2bf(b.y);
    v[6] = (short)f2bf(b.z); v[7] = (short)f2bf(b.w);
    size_t off = (size_t)r * 16384 + (o >> 4) * 2048 + (ko >> 2) * 512 + (ko & 3) * 128 + (o & 15) * 8;
    *(short8*)(wf + off) = v;
}

// root_w -> MFMA B-frag layout, hi plane [0..3] and lo plane [4..7] (hi/lo bf16 split)
__global__ void cvt_rootw_frag(const float* __restrict__ root_w, unsigned short* __restrict__ wrf) {
    int id = blockIdx.x * 256 + threadIdx.x;       // 4*128*16 = 8192 exact
    if (id >= T_TYPES * 128 * 16) return;
    int t = id >> 11, rest = id & 2047;
    int o = rest >> 4, ko = rest & 15;
    const float4* pw = (const float4*)(root_w + (size_t)t * 16384 + o * 128 + ko * 8);
    float4 a = pw[0], b = pw[1];
    float v[8] = {a.x, a.y, a.z, a.w, b.x, b.y, b.z, b.w};
    short8 hi, lo;
    #pragma unroll
    for (int j = 0; j < 8; ++j) {
        unsigned short h = f2bf(v[j]);
        hi[j] = (short)h;
        lo[j] = (short)f2bf(v[j] - bf2f(h));
    }
    size_t off = (size_t)t * 16384 + (o >> 4) * 2048 + (ko >> 2) * 512 + (ko & 3) * 128 + (o & 15) * 8;
    *(short8*)(wrf + off) = hi;
    *(short8*)(wrf + (size_t)T_TYPES * 16384 + off) = lo;
}

// ---------------- root linear, NATURAL node order + local type grouping ----------
// Runs LAST (RMW onto gather's output). ILP-restructured (R7, best measured):
// RMW loads first, 8 parallel ct accumulator chains, store-only epilogue.
__launch_bounds__(256)
__global__ void root_nat(const float* __restrict__ x, const unsigned short* __restrict__ wrf,
                         const float* __restrict__ root_b, const int* __restrict__ tnt,
                         float* __restrict__ out) {
    __shared__ int cnt[T_TYPES];
    __shared__ int goff[T_TYPES];
    __shared__ int rankb[64];
    __shared__ int lidx[112];          // 7 tiles x 16 rows max
    __shared__ int ttyp[8];
    __shared__ int ntile_s;
    int tid = threadIdx.x;
    int base = blockIdx.x * 64;
    if (tid < T_TYPES) cnt[tid] = 0;
    if (tid < 112) lidx[tid] = -1;
    __syncthreads();
    int myt = -1;
    if (tid < 64 && base + tid < N_NODES) {
        myt = tnt[base + tid];
        rankb[tid] = atomicAdd(&cnt[myt], 1);
    }
    __syncthreads();
    if (tid == 0) {
        int s = 0;
        for (int t = 0; t < T_TYPES; ++t) {
            goff[t] = s;
            int nt = (cnt[t] + 15) >> 4;
            for (int k = 0; k < nt; ++k) ttyp[(s >> 4) + k] = t;
            s += nt << 4;
        }
        ntile_s = s >> 4;
    }
    __syncthreads();
    if (myt >= 0) lidx[goff[myt] + rankb[tid]] = base + tid;
    __syncthreads();
    int ntiles = ntile_s;

    int wave = tid >> 6, lane = tid & 63;
    int l16 = lane & 15, kq = lane >> 4;
    for (int tile = wave; tile < ntiles; tile += 4) {
        int t = ttyp[tile];

        int nr0 = lidx[tile * 16 + kq * 4 + 0];
        int nr1 = lidx[tile * 16 + kq * 4 + 1];
        int nr2 = lidx[tile * 16 + kq * 4 + 2];
        int nr3 = lidx[tile * 16 + kq * 4 + 3];

        float ov[8][4];
        #pragma unroll
        for (int ct = 0; ct < 8; ++ct) {
            ov[ct][0] = (nr0 >= 0) ? out[(size_t)nr0 * C_DIM + ct * 16 + l16] : 0.0f;
            ov[ct][1] = (nr1 >= 0) ? out[(size_t)nr1 * C_DIM + ct * 16 + l16] : 0.0f;
            ov[ct][2] = (nr2 >= 0) ? out[(size_t)nr2 * C_DIM + ct * 16 + l16] : 0.0f;
            ov[ct][3] = (nr3 >= 0) ? out[(size_t)nr3 * C_DIM + ct * 16 + l16] : 0.0f;
        }
        float bias[8];
        #pragma unroll
        for (int ct = 0; ct < 8; ++ct) bias[ct] = root_b[t * 128 + ct * 16 + l16];

        int node = lidx[tile * 16 + l16];
        short8 ah[4], al[4];
        #pragma unroll
        for (int kb = 0; kb < 4; ++kb) {
            float v[8];
            if (node >= 0) {
                const float4* px = (const float4*)(x + (size_t)node * C_DIM + kb * 32 + kq * 8);
                float4 p0 = px[0], p1 = px[1];
                v[0] = p0.x; v[1] = p0.y; v[2] = p0.z; v[3] = p0.w;
                v[4] = p1.x; v[5] = p1.y; v[6] = p1.z; v[7] = p1.w;
            } else {
                #pragma unroll
                for (int j = 0; j < 8; ++j) v[j] = 0.0f;
            }
            #pragma unroll
            for (int j = 0; j < 8; ++j) {
                unsigned short h = f2bf(v[j]);
                ah[kb][j] = (short)h;
                al[kb][j] = (short)f2bf(v[j] - bf2f(h));
            }
        }

        const unsigned short* wh = wrf + (size_t)t * 16384;
        const unsigned short* wl = wh + (size_t)T_TYPES * 16384;
        f32x4 acc[8];
        #pragma unroll
        for (int ct = 0; ct < 8; ++ct) acc[ct] = (f32x4)0.0f;
        #pragma unroll
        for (int kb = 0; kb < 4; ++kb) {
            #pragma unroll
            for (int ct = 0; ct < 8; ++ct) {
                short8 bh = *(const short8*)(wh + ct * 2048 + kb * 512 + lane * 8);
                short8 bl = *(const short8*)(wl + ct * 2048 + kb * 512 + lane * 8);
                acc[ct] = __builtin_amdgcn_mfma_f32_16x16x32_bf16(ah[kb], bh, acc[ct], 0, 0, 0);
                acc[ct] = __builtin_amdgcn_mfma_f32_16x16x32_bf16(al[kb], bh, acc[ct], 0, 0, 0);
                acc[ct] = __builtin_amdgcn_mfma_f32_16x16x32_bf16(ah[kb], bl, acc[ct], 0, 0, 0);
            }
        }

        #pragma unroll
        for (int ct = 0; ct < 8; ++ct) {
            if (nr0 >= 0) out[(size_t)nr0 * C_DIM + ct * 16 + l16] = ov[ct][0] + acc[ct][0] + bias[ct];
            if (nr1 >= 0) out[(size_t)nr1 * C_DIM + ct * 16 + l16] = ov[ct][1] + acc[ct][1] + bias[ct];
            if (nr2 >= 0) out[(size_t)nr2 * C_DIM + ct * 16 + l16] = ov[ct][2] + acc[ct][2] + bias[ct];
            if (nr3 >= 0) out[(size_t)nr3 * C_DIM + ct * 16 + l16] = ov[ct][3] + acc[ct][3] + bias[ct];
        }
    }
}

// ---------------- fused MFMA GEMM, all 7 relations, LDS-shared weights ---------
// R10 structure (64-row blocks, R7 store orientation) + the fix the counters
// demanded: each wave was re-reading the full 229 KB wf set from L2 (1.43 GB
// aggregate ~= 41 us at L2 ceiling). Now each relation's 32 KB frag tile is
// staged into LDS ONCE per block and shared by all 4 waves: 4x less L2 read,
// B-frags become conflict-free ds_read_b128 (lane-consecutive 16B = 2-way).
__launch_bounds__(256)
__global__ void xw_gemm_all(const float* __restrict__ x,
                            const unsigned short* __restrict__ wf,
                            unsigned short* __restrict__ xwb7) {
    __shared__ unsigned short wbuf[16384];         // 32 KB: one relation's B-frags
    int tid = threadIdx.x;
    int wave = tid >> 6, lane = tid & 63;
    int m0 = blockIdx.x * 64;
    int l16 = lane & 15, kq = lane >> 4;

    int row = m0 + wave * 16 + l16;
    bool ok = row < N_NODES;
    short8 a[4];
    #pragma unroll
    for (int kb = 0; kb < 4; ++kb) {
        float v[8];
        if (ok) {
            const float4* px = (const float4*)(x + (size_t)row * C_DIM + kb * 32 + kq * 8);
            float4 p0 = px[0], p1 = px[1];
            v[0] = p0.x; v[1] = p0.y; v[2] = p0.z; v[3] = p0.w;
            v[4] = p1.x; v[5] = p1.y; v[6] = p1.z; v[7] = p1.w;
        } else {
            #pragma unroll
            for (int j = 0; j < 8; ++j) v[j] = 0.0f;
        }
        #pragma unroll
        for (int j = 0; j < 8; ++j) a[kb][j] = (short)f2bf(v[j]);
    }

    int col = l16, rq = kq * 4;                    // C/D: col=lane&15,row=(lane>>4)*4+i
    size_t base = (size_t)(m0 + wave * 16 + rq) * C_DIM + col;
    for (int r = 0; r < R_TYPES; ++r) {
        const unsigned short* wr = wf + (size_t)r * 16384;
        __syncthreads();                           // all waves done reading wbuf (r-1)
        #pragma unroll
        for (int c = 0; c < 8; ++c) {              // 256 threads x 8 chunks x 16B = 32 KB
            int chunk = c * 256 + tid;
            *(short8*)&wbuf[chunk * 8] = *(const short8*)(wr + chunk * 8);
        }
        __syncthreads();                           // wbuf ready
        unsigned short* xwb = xwb7 + (size_t)r * XWB_PLANE;
        #pragma unroll
        for (int ct = 0; ct < 8; ++ct) {
            f32x4 acc = (f32x4)0.0f;
            #pragma unroll
            for (int kb = 0; kb < 4; ++kb) {
                short8 b = *(const short8*)&wbuf[ct * 2048 + kb * 512 + lane * 8];
                acc = __builtin_amdgcn_mfma_f32_16x16x32_bf16(a[kb], b, acc, 0, 0, 0);
            }
            #pragma unroll
            for (int i = 0; i < 4; ++i)
                xwb[base + (size_t)i * C_DIM + ct * 16] = f2bf(acc[i]);   // unconditional
        }
    }
}

// fallback per-relation GEMM (single plane), A read directly from x (128-row blocks)
__launch_bounds__(256)
__global__ void xw_gemm_mfma(const float* __restrict__ x,
                             const unsigned short* __restrict__ wf,
                             unsigned short* __restrict__ xwb, int r) {
    int wave = threadIdx.x >> 6, lane = threadIdx.x & 63;
    int m0 = blockIdx.x * 128;
    int l16 = lane & 15, kq = lane >> 4;
    const unsigned short* wr = wf + (size_t)r * 16384;

    short8 a[4][2];
    #pragma unroll
    for (int rt = 0; rt < 2; ++rt) {
        int row = m0 + wave * 32 + rt * 16 + l16;
        bool ok = row < N_NODES;
        #pragma unroll
        for (int kb = 0; kb < 4; ++kb) {
            float v[8];
            if (ok) {
                const float4* px = (const float4*)(x + (size_t)row * C_DIM + kb * 32 + kq * 8);
                float4 p0 = px[0], p1 = px[1];
                v[0] = p0.x; v[1] = p0.y; v[2] = p0.z; v[3] = p0.w;
                v[4] = p1.x; v[5] = p1.y; v[6] = p1.z; v[7] = p1.w;
            } else {
                #pragma unroll
                for (int j = 0; j < 8; ++j) v[j] = 0.0f;
            }
            #pragma unroll
            for (int j = 0; j < 8; ++j) a[kb][rt][j] = (short)f2bf(v[j]);
        }
    }

    int col = l16, rq = kq * 4;
    #pragma unroll
    for (int ct = 0; ct < 8; ++ct) {
        f32x4 acc0 = (f32x4)0.0f, acc1 = (f32x4)0.0f;
        #pragma unroll
        for (int kb = 0; kb < 4; ++kb) {
            short8 b = *(const short8*)(wr + (size_t)ct * 2048 + kb * 512 + lane * 8);
            acc0 = __builtin_amdgcn_mfma_f32_16x16x32_bf16(a[kb][0], b, acc0, 0, 0, 0);
            acc1 = __builtin_amdgcn_mfma_f32_16x16x32_bf16(a[kb][1], b, acc1, 0, 0, 0);
        }
        #pragma unroll
        for (int i = 0; i < 4; ++i) {
            int n0 = m0 + wave * 32 + rq + i;
            if (n0 < N_NODES)
                xwb[(size_t)n0 * C_DIM + ct * 16 + col] = f2bf(acc0[i]);
            int n1 = n0 + 16;
            if (n1 < N_NODES)
                xwb[(size_t)n1 * C_DIM + ct * 16 + col] = f2bf(acc1[i]);
        }
    }
}

// ---------------- fused gather: out[d] = sum over d's edges of xwb7[r][src]*inv
// 16 edges per main iteration: 4 independent uint4 row loads in flight per wave
// (quarter-lane layout: 16 lanes x 16B per row). esrc prefetched one iteration
// ahead. Tail issues its group loads independently. Pure overwrite.
__global__ void gather_fused(const int* __restrict__ dst_off, const int* __restrict__ esrc,
                             const float* __restrict__ inv,
                             const unsigned short* __restrict__ xwb7,
                             float* __restrict__ out) {
    int wave = threadIdx.x >> 6, lane = threadIdx.x & 63;
    int d = blockIdx.x * 4 + wave;
    if (d >= N_NODES) return;
    int o0 = dst_off[d], o1 = dst_off[d + 1];
    int q = lane >> 4;               // quarter: which edge of a 4-group
    int l16 = lane & 15;
    const float* invd = inv + d * R_TYPES;
    float acc[8];
    #pragma unroll
    for (int j = 0; j < 8; ++j) acc[j] = 0.f;

    int e = o0;
    int pk0 = 0, pk1 = 0, pk2 = 0, pk3 = 0;
    bool run = (e + 16 <= o1);
    if (run) {
        pk0 = esrc[e + q];       pk1 = esrc[e + 4 + q];
        pk2 = esrc[e + 8 + q];   pk3 = esrc[e + 12 + q];
    }
    while (run) {
        uint4 r0 = *(const uint4*)(xwb7 + (size_t)(pk0 & 0xFFFFF) * C_DIM + l16 * 8);
        uint4 r1 = *(const uint4*)(xwb7 + (size_t)(pk1 & 0xFFFFF) * C_DIM + l16 * 8);
        uint4 r2 = *(const uint4*)(xwb7 + (size_t)(pk2 & 0xFFFFF) * C_DIM + l16 * 8);
        uint4 r3 = *(const uint4*)(xwb7 + (size_t)(pk3 & 0xFFFFF) * C_DIM + l16 * 8);
        float s0 = invd[pk0 >> 20];
        float s1 = invd[pk1 >> 20];
        float s2 = invd[pk2 >> 20];
        float s3 = invd[pk3 >> 20];
        e += 16;
        run = (e + 16 <= o1);
        if (run) {               // prefetch next iteration's packed indices
            pk0 = esrc[e + q];       pk1 = esrc[e + 4 + q];
            pk2 = esrc[e + 8 + q];   pk3 = esrc[e + 12 + q];
        }
        acc[0] += bf2f(r0.x & 0xffffu) * s0;  acc[1] += bf2f(r0.x >> 16) * s0;
        acc[2] += bf2f(r0.y & 0xffffu) * s0;  acc[3] += bf2f(r0.y >> 16) * s0;
        acc[4] += bf2f(r0.z & 0xffffu) * s0;  acc[5] += bf2f(r0.z >> 16) * s0;
        acc[6] += bf2f(r0.w & 0xffffu) * s0;  acc[7] += bf2f(r0.w >> 16) * s0;
        acc[0] += bf2f(r1.x & 0xffffu) * s1;  acc[1] += bf2f(r1.x >> 16) * s1;
        acc[2] += bf2f(r1.y & 0xffffu) * s1;  acc[3] += bf2f(r1.y >> 16) * s1;
        acc[4] += bf2f(r1.z & 0xffffu) * s1;  acc[5] += bf2f(r1.z >> 16) * s1;
        acc[6] += bf2f(r1.w & 0xffffu) * s1;  acc[7] += bf2f(r1.w >> 16) * s1;
        acc[0] += bf2f(r2.x & 0xffffu) * s2;  acc[1] += bf2f(r2.x >> 16) * s2;
        acc[2] += bf2f(r2.y & 0xffffu) * s2;  acc[3] += bf2f(r2.y >> 16) * s2;
        acc[4] += bf2f(r2.z & 0xffffu) * s2;  acc[5] += bf2f(r2.z >> 16) * s2;
        acc[6] += bf2f(r2.w & 0xffffu) * s2;  acc[7] += bf2f(r2.w >> 16) * s2;
        acc[0] += bf2f(r3.x & 0xffffu) * s3;  acc[1] += bf2f(r3.x >> 16) * s3;
        acc[2] += bf2f(r3.y & 0xffffu) * s3;  acc[3] += bf2f(r3.y >> 16) * s3;
        acc[4] += bf2f(r3.z & 0xffffu) * s3;  acc[5] += bf2f(r3.z >> 16) * s3;
        acc[6] += bf2f(r3.w & 0xffffu) * s3;  acc[7] += bf2f(r3.w >> 16) * s3;
    }
    // tail: 0-15 edges in up to 4 independent groups of 4 (uniform branches)
    #pragma unroll
    for (int j = 0; j < 4; ++j) {
        int eb = e + j * 4;
        if (eb < o1) {
            int idx = eb + q;
            bool valid = idx < o1;
            int pk = esrc[valid ? idx : eb];       // eb < o1: safe clamp
            uint4 rw = *(const uint4*)(xwb7 + (size_t)(pk & 0xFFFFF) * C_DIM + l16 * 8);
            float s = valid ? invd[pk >> 20] : 0.0f;
            acc[0] += bf2f(rw.x & 0xffffu) * s;  acc[1] += bf2f(rw.x >> 16) * s;
            acc[2] += bf2f(rw.y & 0xffffu) * s;  acc[3] += bf2f(rw.y >> 16) * s;
            acc[4] += bf2f(rw.z & 0xffffu) * s;  acc[5] += bf2f(rw.z >> 16) * s;
            acc[6] += bf2f(rw.w & 0xffffu) * s;  acc[7] += bf2f(rw.w >> 16) * s;
        }
    }

    #pragma unroll
    for (int j = 0; j < 8; ++j) {
        acc[j] += __shfl_xor(acc[j], 16);
        acc[j] += __shfl_xor(acc[j], 32);
    }
    if (lane < 32) {
        int fidx = (l16 << 1) | q;                 // q in {0,1} for lane<32
        float4 w = (lane < 16) ? make_float4(acc[0], acc[1], acc[2], acc[3])
                               : make_float4(acc[4], acc[5], acc[6], acc[7]);
        ((float4*)(out + (size_t)d * C_DIM))[fidx] = w;   // full overwrite
    }
}

// ---------------- fallback gather (single xwb plane, filter by r, RMW out) -----
__global__ void gather_rel_f(const int* __restrict__ dst_off, const int* __restrict__ esrc,
                             const float* __restrict__ inv,
                             const unsigned short* __restrict__ xwb,
                             float* __restrict__ out, int rf) {
    int wave = threadIdx.x >> 6, lane = threadIdx.x & 63;
    int d = blockIdx.x * 4 + wave;
    if (d >= N_NODES) return;
    int o0 = dst_off[d], o1 = dst_off[d + 1];
    float ax = 0.0f, ay = 0.0f;
    bool any = false;
    for (int e = o0; e < o1; ++e) {
        int pk = esrc[e];
        if ((pk >> 20) != rf) continue;
        any = true;
        int src = (pk & 0xFFFFF) - rf * XP_ROWS;
        unsigned int row = *(const unsigned int*)(xwb + (size_t)src * C_DIM + lane * 2);
        ax += bf2f(row & 0xffffu);
        ay += bf2f(row >> 16);
    }
    if (!any) return;
    float sc = inv[d * R_TYPES + rf];
    float2* po = (float2*)(out + (size_t)d * C_DIM) + lane;
    float2 v = *po;
    v.x += ax * sc;
    v.y += ay * sc;
    *po = v;
}

extern "C" void kernel_launch(void* const* d_in, const int* in_sizes, int n_in,
                              void* d_out, int out_size, void* d_ws, size_t ws_size,
                              hipStream_t stream) {
    const float* x      = (const float*)d_in[0];
    const int*   ei     = (const int*)d_in[1];
    const int*   et     = (const int*)d_in[2];
    const int*   tnt    = (const int*)d_in[3];
    const float* rel_w  = (const float*)d_in[4];
    const float* root_w = (const float*)d_in[5];
    const float* root_b = (const float*)d_in[6];
    float* out = (float*)d_out;

    char* ws = (char*)d_ws;
    int*   cnti    = (int*)(ws + OFF_CNTI);
    float* inv     = (float*)(ws + OFF_INV);
    int*   dst_off = (int*)(ws + OFF_DOFF);
    int*   cursor  = (int*)(ws + OFF_CURS);
    int*   bsum    = (int*)(ws + OFF_BSUM);
    int*   esrc    = (int*)(ws + OFF_ESRC);
    unsigned short* wf  = (unsigned short*)(ws + OFF_WF);
    unsigned short* xwb = (unsigned short*)(ws + OFF_XWB);
    unsigned short* wrf = (unsigned short*)(ws + OFF_WRF);   // in old perm region

    const bool full = (ws_size >= FULL_NEED);   // constant across calls: graph-safe

    hipMemsetAsync(ws + OFF_CNTI, 0, SEGS * sizeof(int), stream);
    if (!full)
        hipMemsetAsync(d_out, 0, (size_t)out_size * sizeof(float), stream);

    cvt_rootw_frag<<<32, 256, 0, stream>>>(root_w, wrf);

    // dst-CSR sort of edges
    edge_hist  <<<NB_E, 256, 0, stream>>>(ei, et, cnti);
    inv_kernel <<<(SEGS + 255) / 256, 256, 0, stream>>>(cnti, inv);
    dst_scan1  <<<NB_N, 256, 0, stream>>>(cnti, dst_off, bsum);
    seg_scan2  <<<1, 256, 0, stream>>>(bsum, NB_N);
    dst_scan3  <<<NB_N, 256, 0, stream>>>(dst_off, cursor, bsum);
    place_edges<<<NB_E * 8, 256, 0, stream>>>(ei, et, cursor, esrc);

    cvt_w_frag<<<56, 256, 0, stream>>>(rel_w, wf);

    if (full) {
        xw_gemm_all <<<XP_ROWS / 64, 256, 0, stream>>>(x, wf, xwb);
        gather_fused<<<(N_NODES + 3) / 4, 256, 0, stream>>>(dst_off, esrc, inv, xwb, out);
    } else {
        for (int r = 0; r < R_TYPES; ++r) {
            xw_gemm_mfma<<<XP_ROWS / 128, 256, 0, stream>>>(x, wf, xwb, r);
            gather_rel_f<<<(N_NODES + 3) / 4, 256, 0, stream>>>(dst_off, esrc, inv, xwb, out, r);
        }
    }
    // root linear last: RMW onto gather's output
    root_nat<<<NB_ROOT, 256, 0, stream>>>(x, wrf, root_b, tnt, out);
}